// Round 9
// baseline (132.805 us; speedup 1.0000x reference)
//
#include <hip/hip_runtime.h>
#include <hip/hip_bf16.h>

// out = (Q K^T) V * scale, softmax discarded => associativity:
//   out_i = Q_i @ (K_i^T @ V_i) * scale over 32 blocks of 2048 flat rows of
//   the (65536,64) view of the (4096,1024) projections.
// R9: reduce_T eliminated — kT atomically accumulates fp32 T (zeroed in cvt);
// qT converts T->bf16 at staging. kT 512 wgs. 4 kernels total.

#define E_DIM 1024
#define N_ROWS 4096

typedef __attribute__((ext_vector_type(8))) short bf16x8;
typedef __attribute__((ext_vector_type(4))) float f32x4;

// ---- ws layout ----
// ushort: QB 0, KB 4194304, VB 8388608, XB 12582912, WB 16777216..19922944
// float:  TF at P_F (32 x 64 x 64 fp32 accumulator, [d][e])
#define QB_U 0
#define KB_U 4194304
#define VB_U 8388608
#define XB_U 12582912
#define WB_U 16777216
#define P_F  9961472

__device__ __forceinline__ unsigned short f2b(float f) {
    union { float f; unsigned int i; } c; c.f = f;
    unsigned int r = c.i + 0x7FFFu + ((c.i >> 16) & 1u);   // RNE (finite data)
    return (unsigned short)(r >> 16);
}

typedef __attribute__((address_space(1))) const void* gptr_t;
typedef __attribute__((address_space(3))) void* lptr_t;
__device__ __forceinline__ void gl_lds16(const void* g, void* l) {
    __builtin_amdgcn_global_load_lds((gptr_t)g, (lptr_t)l, 16, 0, 0);
}

// ---------------------------------------------------------------------------
// Kernel 0: fp32 -> bf16 convert (segs 0-6) + zero the fp32 T accumulator
// (seg 7; ws is re-poisoned 0xAA before every launch).
// ---------------------------------------------------------------------------
__global__ __launch_bounds__(256) void cvt_bf16(
    const float* __restrict__ x,  const float* __restrict__ wq,
    const float* __restrict__ wk, const float* __restrict__ wv,
    unsigned short* __restrict__ dst0, float* __restrict__ Tzero)
{
    const int seg = blockIdx.y;
    if (seg == 7) {
        Tzero[blockIdx.x * 256 + threadIdx.x] = 0.0f;   // 512*256 = 131072 = 32*4096
        return;
    }
    const float* __restrict__ src;
    unsigned short* __restrict__ dst;
    if (seg < 4) { src = x + (size_t)seg * 1048576; dst = dst0 + (size_t)seg * 1048576; }
    else {
        src = (seg == 4) ? wq : (seg == 5) ? wk : wv;
        dst = dst0 + 4194304 + (size_t)(seg - 4) * 1048576;
    }
    const int i = blockIdx.x * 256 + threadIdx.x;   // 0..131071
    const float4 a = *(const float4*)(src + (size_t)i * 8);
    const float4 b = *(const float4*)(src + (size_t)i * 8 + 4);
    uint4 o;
    o.x = (unsigned)f2b(a.x) | ((unsigned)f2b(a.y) << 16);
    o.y = (unsigned)f2b(a.z) | ((unsigned)f2b(a.w) << 16);
    o.z = (unsigned)f2b(b.x) | ((unsigned)f2b(b.y) << 16);
    o.w = (unsigned)f2b(b.z) | ((unsigned)f2b(b.w) << 16);
    *(uint4*)(dst + (size_t)i * 8) = o;
}

// ---------------------------------------------------------------------------
// Kernel A: Y(bf16) = Xb @ Wb^T + bias (blockIdx.z selects weight).
// 128x128 tile, BK=32, global_load_lds x16, 16x16x32 bf16 MFMA, fp32 acc.
// XOR-swizzled LDS (2-way fragment reads).
// ---------------------------------------------------------------------------
__global__ __launch_bounds__(256, 3) void qkv_gemm_mfma(
    const unsigned short* __restrict__ Xb,
    const unsigned short* __restrict__ Wb,
    const float* __restrict__ bq, const float* __restrict__ bk,
    const float* __restrict__ bv,
    unsigned short* __restrict__ qkv)
{
    const int which = blockIdx.z;
    const unsigned short* __restrict__ W = Wb + (size_t)which * (1024 * 1024);
    const float* __restrict__ bias = (which == 0) ? bq : (which == 1) ? bk : bv;
    unsigned short* __restrict__ Y = qkv + (size_t)which * ((size_t)N_ROWS * E_DIM);

    __shared__ __align__(16) unsigned short Als[128 * 32];
    __shared__ __align__(16) unsigned short Bls[128 * 32];

    const int tid  = threadIdx.x;
    const int w    = tid >> 6;
    const int lane = tid & 63;
    const int m0 = blockIdx.x * 128;
    const int n0 = blockIdx.y * 128;
    const int wm = (w >> 1) * 64;
    const int wn = (w & 1) * 64;

    f32x4 acc[4][4];
    #pragma unroll
    for (int i = 0; i < 4; ++i)
        #pragma unroll
        for (int j = 0; j < 4; ++j)
            acc[i][j] = f32x4{0.f, 0.f, 0.f, 0.f};

    const int srow = w * 32 + (lane >> 2);
    const int skc  = ((lane & 3) ^ ((lane >> 3) & 3)) * 8;
    const int quad = lane >> 4;
    const int fm   = lane & 15;
    const int sw2  = (fm >> 1) & 3;

    for (int k0 = 0; k0 < E_DIM; k0 += 32) {
        gl_lds16((const void*)(Xb + (size_t)(m0 + srow) * E_DIM + k0 + skc),
                 (void*)((char*)Als + (w * 2 + 0) * 1024));
        gl_lds16((const void*)(Xb + (size_t)(m0 + srow + 16) * E_DIM + k0 + skc),
                 (void*)((char*)Als + (w * 2 + 1) * 1024));
        gl_lds16((const void*)(W + (size_t)(n0 + srow) * E_DIM + k0 + skc),
                 (void*)((char*)Bls + (w * 2 + 0) * 1024));
        gl_lds16((const void*)(W + (size_t)(n0 + srow + 16) * E_DIM + k0 + skc),
                 (void*)((char*)Bls + (w * 2 + 1) * 1024));
        __syncthreads();

        const int slot = (quad ^ sw2) * 8;
        bf16x8 af[4], bf[4];
        #pragma unroll
        for (int t = 0; t < 4; ++t) {
            af[t] = *(const bf16x8*)(Als + (wm + t * 16 + fm) * 32 + slot);
            bf[t] = *(const bf16x8*)(Bls + (wn + t * 16 + fm) * 32 + slot);
        }
        #pragma unroll
        for (int rt = 0; rt < 4; ++rt)
            #pragma unroll
            for (int ct = 0; ct < 4; ++ct)
                acc[rt][ct] = __builtin_amdgcn_mfma_f32_16x16x32_bf16(
                    af[rt], bf[ct], acc[rt][ct], 0, 0, 0);
        __syncthreads();
    }

    float bcol[4];
    #pragma unroll
    for (int ct = 0; ct < 4; ++ct) bcol[ct] = bias[n0 + wn + ct * 16 + fm];

    const int rbase = (lane >> 4) * 4;
    #pragma unroll
    for (int rt = 0; rt < 4; ++rt) {
        #pragma unroll
        for (int ct = 0; ct < 4; ++ct) {
            #pragma unroll
            for (int r = 0; r < 4; ++r) {
                const int row = m0 + wm + rt * 16 + rbase + r;
                const int col = n0 + wn + ct * 16 + fm;
                Y[(size_t)row * E_DIM + col] = f2b(acc[rt][ct][r] + bcol[ct]);
            }
        }
    }
}

// swizzled index into a [row][64] LDS tile (8 slots of 8 elems per row)
__device__ __forceinline__ int sw_idx(int row, int r) {
    return row * 64 + (((((r) >> 3) & 7) ^ (row & 7)) << 3) + (r & 7);
}

// ---------------------------------------------------------------------------
// Kernel B: kT via MFMA + device-scope fp32 atomicAdd into T[i][d][e].
// Block (i, c): 128-row chunk. K,V staged transposed+swizzled in LDS;
// D[m=d][n=e] = sum_k A[m][k]B[n][k], A=Vt rows, B=Kt rows.
// ---------------------------------------------------------------------------
__global__ __launch_bounds__(256) void kT_mfma(
    const unsigned short* __restrict__ qkv, float* __restrict__ TF)
{
    const size_t base = (size_t)blockIdx.x * (2048 * 64) + (size_t)blockIdx.y * (128 * 64);
    const unsigned short* __restrict__ Kb = qkv + KB_U + base;
    const unsigned short* __restrict__ Vb = qkv + VB_U + base;
    float* __restrict__ Tf = TF + (size_t)blockIdx.x * 4096;

    __shared__ __align__(16) unsigned short Kt[64 * 64];  // [e][r] swizzled
    __shared__ __align__(16) unsigned short Vt[64 * 64];  // [d][r] swizzled

    const int tid  = threadIdx.x;
    const int w    = tid >> 6;
    const int lane = tid & 63;
    const int rl   = tid & 63;
    const int eo   = (tid >> 6) * 16;
    const int quad = lane >> 4;
    const int fm   = lane & 15;
    const int sw8  = fm & 7;

    f32x4 acc[4];
    #pragma unroll
    for (int nt = 0; nt < 4; ++nt) acc[nt] = f32x4{0.f, 0.f, 0.f, 0.f};

    for (int rb = 0; rb < 128; rb += 64) {
        union { uint4 u; unsigned short s[8]; } k0, k1, v0, v1;
        const size_t ga = (size_t)(rb + rl) * 64 + eo;
        k0.u = *(const uint4*)(Kb + ga);
        k1.u = *(const uint4*)(Kb + ga + 8);
        v0.u = *(const uint4*)(Vb + ga);
        v1.u = *(const uint4*)(Vb + ga + 8);
        __syncthreads();
        #pragma unroll
        for (int j = 0; j < 8; ++j) {
            Kt[sw_idx(eo + j, rl)]     = k0.s[j];
            Kt[sw_idx(eo + 8 + j, rl)] = k1.s[j];
            Vt[sw_idx(eo + j, rl)]     = v0.s[j];
            Vt[sw_idx(eo + 8 + j, rl)] = v1.s[j];
        }
        __syncthreads();
        #pragma unroll
        for (int kk = 0; kk < 2; ++kk) {
            const int slot = ((kk * 4 + quad) ^ sw8) << 3;
            const bf16x8 af = *(const bf16x8*)(Vt + (w * 16 + fm) * 64 + slot);
            #pragma unroll
            for (int nt = 0; nt < 4; ++nt) {
                const bf16x8 bf = *(const bf16x8*)(Kt + (nt * 16 + fm) * 64 + slot);
                acc[nt] = __builtin_amdgcn_mfma_f32_16x16x32_bf16(af, bf, acc[nt], 0, 0, 0);
            }
        }
    }

    // accumulate partial into fp32 T: d = w*16 + (lane>>4)*4 + r, e = nt*16+fm
    const int rbase = (lane >> 4) * 4;
    #pragma unroll
    for (int nt = 0; nt < 4; ++nt)
        #pragma unroll
        for (int r = 0; r < 4; ++r)
            atomicAdd(&Tf[(size_t)(w * 16 + rbase + r) * 64 + nt * 16 + fm],
                      acc[nt][r]);
}

// ---------------------------------------------------------------------------
// Kernel C: out = 0.125 * Qflat @ Tt^T (MFMA mini-GEMM, K=64).
// A (Q rows) via swizzled gl_lds16; B staged from fp32 T with convert+swizzle.
// ---------------------------------------------------------------------------
__global__ __launch_bounds__(256, 2) void qT_mfma(
    const unsigned short* __restrict__ qkv,
    const float* __restrict__ TF,
    float* __restrict__ out)
{
    __shared__ __align__(16) unsigned short Als[128 * 64];  // 16 KB: Q rows
    __shared__ __align__(16) unsigned short Bls[64 * 64];   //  8 KB: Tt rows

    const int bx   = blockIdx.x;        // 0..511
    const int r0   = bx * 128;
    const int i    = bx >> 4;
    const int tid  = threadIdx.x;
    const int w    = tid >> 6;
    const int lane = tid & 63;
    const int quad = lane >> 4;
    const int fm   = lane & 15;
    const int sw8  = fm & 7;

    const unsigned short* __restrict__ Qb = qkv + QB_U + (size_t)r0 * 64;
    const float* __restrict__ Tf = TF + (size_t)i * 4096;

    // A: async swizzled staging
    const int soff = (lane >> 3) * 64 + (((lane & 7) ^ ((lane >> 3) & 7)) << 3);
    #pragma unroll
    for (int c = 0; c < 4; ++c)
        gl_lds16((const void*)(Qb + (w * 4 + c) * 512 + soff),
                 (void*)((char*)Als + (w * 4 + c) * 1024));

    // B: fp32 T -> bf16, swizzled. Thread t: row d = t>>2, elems [q4*16, +16).
    {
        const int d  = tid >> 2;
        const int e0 = (tid & 3) * 16;
        float tv[16];
        #pragma unroll
        for (int j = 0; j < 4; ++j)
            *(float4*)&tv[j * 4] = *(const float4*)(Tf + d * 64 + e0 + j * 4);
        #pragma unroll
        for (int s = 0; s < 2; ++s) {
            union { uint4 u; unsigned short h[8]; } pk;
            #pragma unroll
            for (int j = 0; j < 8; ++j) pk.h[j] = f2b(tv[s * 8 + j]);
            const int slot = (e0 >> 3) + s;
            *(uint4*)(Bls + d * 64 + ((slot ^ (d & 7)) << 3)) = pk.u;
        }
    }
    __syncthreads();

    bf16x8 af[2][2], bf[4][2];
    #pragma unroll
    for (int mt = 0; mt < 2; ++mt)
        #pragma unroll
        for (int kk = 0; kk < 2; ++kk)
            af[mt][kk] = *(const bf16x8*)(Als + (w * 32 + mt * 16 + fm) * 64
                                          + (((kk * 4 + quad) ^ sw8) << 3));
    #pragma unroll
    for (int nt = 0; nt < 4; ++nt)
        #pragma unroll
        for (int kk = 0; kk < 2; ++kk)
            bf[nt][kk] = *(const bf16x8*)(Bls + (nt * 16 + fm) * 64
                                          + (((kk * 4 + quad) ^ sw8) << 3));

    f32x4 acc[2][4];
    #pragma unroll
    for (int mt = 0; mt < 2; ++mt)
        #pragma unroll
        for (int nt = 0; nt < 4; ++nt)
            acc[mt][nt] = f32x4{0.f, 0.f, 0.f, 0.f};

    #pragma unroll
    for (int kk = 0; kk < 2; ++kk)
        #pragma unroll
        for (int mt = 0; mt < 2; ++mt)
            #pragma unroll
            for (int nt = 0; nt < 4; ++nt)
                acc[mt][nt] = __builtin_amdgcn_mfma_f32_16x16x32_bf16(
                    af[mt][kk], bf[nt][kk], acc[mt][nt], 0, 0, 0);

    const int rbase = (lane >> 4) * 4;
    #pragma unroll
    for (int mt = 0; mt < 2; ++mt) {
        #pragma unroll
        for (int nt = 0; nt < 4; ++nt) {
            #pragma unroll
            for (int r = 0; r < 4; ++r) {
                const int row = r0 + w * 32 + mt * 16 + rbase + r;
                const int col = nt * 16 + fm;
                out[(size_t)row * 64 + col] = 0.125f * acc[mt][nt][r];
            }
        }
    }
}

extern "C" void kernel_launch(void* const* d_in, const int* in_sizes, int n_in,
                              void* d_out, int out_size, void* d_ws, size_t ws_size,
                              hipStream_t stream)
{
    const float* x  = (const float*)d_in[0];
    const float* Wq = (const float*)d_in[1];
    const float* bq = (const float*)d_in[2];
    const float* Wk = (const float*)d_in[3];
    const float* bk = (const float*)d_in[4];
    const float* Wv = (const float*)d_in[5];
    const float* bv = (const float*)d_in[6];
    float* wsf = (float*)d_ws;
    unsigned short* wsu = (unsigned short*)d_ws;
    float* out = (float*)d_out;

    dim3 gCvt(512, 8);
    cvt_bf16<<<gCvt, 256, 0, stream>>>(x, Wq, Wk, Wv, wsu + XB_U, wsf + P_F);

    dim3 gA(N_ROWS / 128, E_DIM / 128, 3);   // 32 x 8 x 3
    qkv_gemm_mfma<<<gA, 256, 0, stream>>>(wsu + XB_U, wsu + WB_U,
                                          bq, bk, bv, wsu + QB_U);

    dim3 gB(32, 16);
    kT_mfma<<<gB, 256, 0, stream>>>(wsu, wsf + P_F);

    qT_mfma<<<512, 256, 0, stream>>>(wsu, wsf + P_F, out);
}

// Round 10
// 124.900 us; speedup vs baseline: 1.0633x; 1.0633x over previous
//
#include <hip/hip_runtime.h>
#include <hip/hip_bf16.h>

// out = (Q K^T) V * scale, softmax discarded => associativity:
//   out_i = Q_i @ (K_i^T @ V_i) * scale over 32 blocks of 2048 flat rows of
//   the (65536,64) view of the (4096,1024) projections.
// R10: revert R9 atomics (back to R8 tail); GEMM BK 32->64 (barriers halved,
// 32 KB LDS, still 3 blocks/CU).

#define E_DIM 1024
#define N_ROWS 4096

typedef __attribute__((ext_vector_type(8))) short bf16x8;
typedef __attribute__((ext_vector_type(4))) float f32x4;

// ---- ws layout (bytes) ----
// QB [0,8.4M) KB [8.4,16.8M) VB [16.8,25.2M) bf16
// XB [25.2,33.6M) WB [33.6,39.8M) bf16
// P  [39.8,44M) fp32 (32 blk x 8 chunks x 4096, [d][e])
// TB [48.2,48.5M) bf16 Tt[32][d=64][e=64]
#define QB_U 0
#define KB_U 4194304
#define VB_U 8388608
#define XB_U 12582912
#define WB_U 16777216
#define P_F  9961472
#define TB_U 24117248

__device__ __forceinline__ unsigned short f2b(float f) {
    union { float f; unsigned int i; } c; c.f = f;
    unsigned int r = c.i + 0x7FFFu + ((c.i >> 16) & 1u);   // RNE (finite data)
    return (unsigned short)(r >> 16);
}

typedef __attribute__((address_space(1))) const void* gptr_t;
typedef __attribute__((address_space(3))) void* lptr_t;
__device__ __forceinline__ void gl_lds16(const void* g, void* l) {
    __builtin_amdgcn_global_load_lds((gptr_t)g, (lptr_t)l, 16, 0, 0);
}

// ---------------------------------------------------------------------------
// Kernel 0: fp32 -> bf16 convert: x (4 MB-segs) + Wq/Wk/Wv.
// ---------------------------------------------------------------------------
__global__ __launch_bounds__(256) void cvt_bf16(
    const float* __restrict__ x,  const float* __restrict__ wq,
    const float* __restrict__ wk, const float* __restrict__ wv,
    unsigned short* __restrict__ dst0)
{
    const int seg = blockIdx.y;
    const float* __restrict__ src;
    unsigned short* __restrict__ dst;
    if (seg < 4) { src = x + (size_t)seg * 1048576; dst = dst0 + (size_t)seg * 1048576; }
    else {
        src = (seg == 4) ? wq : (seg == 5) ? wk : wv;
        dst = dst0 + 4194304 + (size_t)(seg - 4) * 1048576;
    }
    const int i = blockIdx.x * 256 + threadIdx.x;   // 0..131071
    const float4 a = *(const float4*)(src + (size_t)i * 8);
    const float4 b = *(const float4*)(src + (size_t)i * 8 + 4);
    uint4 o;
    o.x = (unsigned)f2b(a.x) | ((unsigned)f2b(a.y) << 16);
    o.y = (unsigned)f2b(a.z) | ((unsigned)f2b(a.w) << 16);
    o.z = (unsigned)f2b(b.x) | ((unsigned)f2b(b.y) << 16);
    o.w = (unsigned)f2b(b.z) | ((unsigned)f2b(b.w) << 16);
    *(uint4*)(dst + (size_t)i * 8) = o;
}

// ---------------------------------------------------------------------------
// Kernel A: Y(bf16) = Xb @ Wb^T + bias (blockIdx.z selects weight).
// 128x128 tile, BK=64 (32 KB LDS, 16 K-iters, barriers halved vs BK=32),
// global_load_lds x16, 16x16x32 bf16 MFMA, fp32 acc, XOR-swizzled LDS.
// LDS row r (64 elems), slot s holds global k-chunk s ^ (r&7).
// ---------------------------------------------------------------------------
__global__ __launch_bounds__(256, 3) void qkv_gemm_mfma(
    const unsigned short* __restrict__ Xb,
    const unsigned short* __restrict__ Wb,
    const float* __restrict__ bq, const float* __restrict__ bk,
    const float* __restrict__ bv,
    unsigned short* __restrict__ qkv)
{
    const int which = blockIdx.z;
    const unsigned short* __restrict__ W = Wb + (size_t)which * (1024 * 1024);
    const float* __restrict__ bias = (which == 0) ? bq : (which == 1) ? bk : bv;
    unsigned short* __restrict__ Y = qkv + (size_t)which * ((size_t)N_ROWS * E_DIM);

    __shared__ __align__(16) unsigned short Als[128 * 64];  // 16 KB
    __shared__ __align__(16) unsigned short Bls[128 * 64];  // 16 KB

    const int tid  = threadIdx.x;
    const int w    = tid >> 6;
    const int lane = tid & 63;
    const int m0 = blockIdx.x * 128;
    const int n0 = blockIdx.y * 128;
    const int wm = (w >> 1) * 64;
    const int wn = (w & 1) * 64;

    f32x4 acc[4][4];
    #pragma unroll
    for (int i = 0; i < 4; ++i)
        #pragma unroll
        for (int j = 0; j < 4; ++j)
            acc[i][j] = f32x4{0.f, 0.f, 0.f, 0.f};

    // staging: call c covers 8 rows; lane -> row (lane>>3), LDS slot lane&7,
    // fetching global k-chunk (lane&7) ^ (lane>>3)  [row&7 == lane>>3]
    const int srow = lane >> 3;                       // 0..7
    const int skc  = ((lane & 7) ^ (lane >> 3)) * 8;  // swizzled global chunk
    const int quad = lane >> 4;
    const int fm   = lane & 15;
    const int sw8  = fm & 7;

    for (int k0 = 0; k0 < E_DIM; k0 += 64) {
        #pragma unroll
        for (int c = 0; c < 4; ++c) {
            const int r = w * 32 + c * 8;
            gl_lds16((const void*)(Xb + (size_t)(m0 + r + srow) * E_DIM + k0 + skc),
                     (void*)((char*)Als + r * 128 + lane * 16));
            gl_lds16((const void*)(W + (size_t)(n0 + r + srow) * E_DIM + k0 + skc),
                     (void*)((char*)Bls + r * 128 + lane * 16));
        }
        __syncthreads();

        #pragma unroll
        for (int kk = 0; kk < 2; ++kk) {
            const int slot = ((kk * 4 + quad) ^ sw8) * 8;
            bf16x8 af[4], bf[4];
            #pragma unroll
            for (int t = 0; t < 4; ++t) {
                af[t] = *(const bf16x8*)(Als + (wm + t * 16 + fm) * 64 + slot);
                bf[t] = *(const bf16x8*)(Bls + (wn + t * 16 + fm) * 64 + slot);
            }
            #pragma unroll
            for (int rt = 0; rt < 4; ++rt)
                #pragma unroll
                for (int ct = 0; ct < 4; ++ct)
                    acc[rt][ct] = __builtin_amdgcn_mfma_f32_16x16x32_bf16(
                        af[rt], bf[ct], acc[rt][ct], 0, 0, 0);
        }
        __syncthreads();
    }

    float bcol[4];
    #pragma unroll
    for (int ct = 0; ct < 4; ++ct) bcol[ct] = bias[n0 + wn + ct * 16 + fm];

    const int rbase = (lane >> 4) * 4;
    #pragma unroll
    for (int rt = 0; rt < 4; ++rt) {
        #pragma unroll
        for (int ct = 0; ct < 4; ++ct) {
            #pragma unroll
            for (int r = 0; r < 4; ++r) {
                const int row = m0 + wm + rt * 16 + rbase + r;
                const int col = n0 + wn + ct * 16 + fm;
                Y[(size_t)row * E_DIM + col] = f2b(acc[rt][ct][r] + bcol[ct]);
            }
        }
    }
}

// swizzled index into a [row][64] LDS tile (8 slots of 8 elems per row)
__device__ __forceinline__ int sw_idx(int row, int r) {
    return row * 64 + (((((r) >> 3) & 7) ^ (row & 7)) << 3) + (r & 7);
}

// ---------------------------------------------------------------------------
// Kernel B: kT via MFMA. Block (i, c): 256-row chunk of attention block i.
//   Ppart[d][e] = sum_{r in chunk} V[r][d] * K[r][e]
// K,V staged transposed+swizzled in LDS; D[m=d][n=e] = sum_k A[m][k]B[n][k].
// ---------------------------------------------------------------------------
__global__ __launch_bounds__(256) void kT_mfma(
    const unsigned short* __restrict__ qkv, float* __restrict__ P)
{
    const size_t base = (size_t)blockIdx.x * (2048 * 64) + (size_t)blockIdx.y * (256 * 64);
    const unsigned short* __restrict__ Kb = qkv + KB_U + base;
    const unsigned short* __restrict__ Vb = qkv + VB_U + base;
    float* __restrict__ Pout = P + ((size_t)blockIdx.x * 8 + blockIdx.y) * 4096;

    __shared__ __align__(16) unsigned short Kt[64 * 64];  // [e][r] swizzled
    __shared__ __align__(16) unsigned short Vt[64 * 64];  // [d][r] swizzled

    const int tid  = threadIdx.x;
    const int w    = tid >> 6;
    const int lane = tid & 63;
    const int rl   = tid & 63;
    const int eo   = (tid >> 6) * 16;
    const int quad = lane >> 4;
    const int fm   = lane & 15;
    const int sw8  = fm & 7;

    f32x4 acc[4];
    #pragma unroll
    for (int nt = 0; nt < 4; ++nt) acc[nt] = f32x4{0.f, 0.f, 0.f, 0.f};

    for (int rb = 0; rb < 256; rb += 64) {
        union { uint4 u; unsigned short s[8]; } k0, k1, v0, v1;
        const size_t ga = (size_t)(rb + rl) * 64 + eo;
        k0.u = *(const uint4*)(Kb + ga);
        k1.u = *(const uint4*)(Kb + ga + 8);
        v0.u = *(const uint4*)(Vb + ga);
        v1.u = *(const uint4*)(Vb + ga + 8);
        __syncthreads();
        #pragma unroll
        for (int j = 0; j < 8; ++j) {
            Kt[sw_idx(eo + j, rl)]     = k0.s[j];
            Kt[sw_idx(eo + 8 + j, rl)] = k1.s[j];
            Vt[sw_idx(eo + j, rl)]     = v0.s[j];
            Vt[sw_idx(eo + 8 + j, rl)] = v1.s[j];
        }
        __syncthreads();
        #pragma unroll
        for (int kk = 0; kk < 2; ++kk) {
            const int slot = ((kk * 4 + quad) ^ sw8) << 3;
            const bf16x8 af = *(const bf16x8*)(Vt + (w * 16 + fm) * 64 + slot);
            #pragma unroll
            for (int nt = 0; nt < 4; ++nt) {
                const bf16x8 bf = *(const bf16x8*)(Kt + (nt * 16 + fm) * 64 + slot);
                acc[nt] = __builtin_amdgcn_mfma_f32_16x16x32_bf16(af, bf, acc[nt], 0, 0, 0);
            }
        }
    }

    const int rbase = (lane >> 4) * 4;
    #pragma unroll
    for (int nt = 0; nt < 4; ++nt)
        #pragma unroll
        for (int r = 0; r < 4; ++r)
            Pout[(size_t)(w * 16 + rbase + r) * 64 + nt * 16 + fm] = acc[nt][r];
}

// ---------------------------------------------------------------------------
// Kernel C0: reduce 8 partials -> Tt bf16: TB[i][d][e]
// ---------------------------------------------------------------------------
__global__ __launch_bounds__(256) void reduce_T(
    const float* __restrict__ P, unsigned short* __restrict__ TB)
{
    const int idx = blockIdx.x * 256 + threadIdx.x;  // 0..131071
    const int i   = idx >> 12;
    const int off = idx & 4095;          // d*64 + e
    const float* p = P + (size_t)i * 8 * 4096 + off;
    float s = 0.0f;
    #pragma unroll
    for (int c = 0; c < 8; ++c) s += p[(size_t)c * 4096];
    TB[(size_t)i * 4096 + off] = f2b(s);
}

// ---------------------------------------------------------------------------
// Kernel C: out = 0.125 * Qflat @ Tt^T (MFMA mini-GEMM, K=64).
// Staging via gl_lds16 with source permutation == same XOR swizzle.
// ---------------------------------------------------------------------------
__global__ __launch_bounds__(256, 2) void qT_mfma(
    const unsigned short* __restrict__ qkv,
    const unsigned short* __restrict__ TB,
    float* __restrict__ out)
{
    __shared__ __align__(16) unsigned short Als[128 * 64];  // 16 KB: Q rows
    __shared__ __align__(16) unsigned short Bls[64 * 64];   //  8 KB: Tt rows

    const int bx   = blockIdx.x;        // 0..511
    const int r0   = bx * 128;
    const int i    = bx >> 4;
    const int tid  = threadIdx.x;
    const int w    = tid >> 6;
    const int lane = tid & 63;
    const int quad = lane >> 4;
    const int fm   = lane & 15;
    const int sw8  = fm & 7;

    const unsigned short* __restrict__ Qb = qkv + QB_U + (size_t)r0 * 64;
    const unsigned short* __restrict__ Tb = TB + (size_t)i * 4096;

    const int soff = (lane >> 3) * 64 + (((lane & 7) ^ (lane >> 3)) << 3);
    #pragma unroll
    for (int c = 0; c < 4; ++c)
        gl_lds16((const void*)(Qb + (w * 4 + c) * 512 + soff),
                 (void*)((char*)Als + (w * 4 + c) * 1024));
    #pragma unroll
    for (int c = 0; c < 2; ++c)
        gl_lds16((const void*)(Tb + (w * 2 + c) * 512 + soff),
                 (void*)((char*)Bls + (w * 2 + c) * 1024));
    __syncthreads();

    bf16x8 af[2][2], bf[4][2];
    #pragma unroll
    for (int mt = 0; mt < 2; ++mt)
        #pragma unroll
        for (int kk = 0; kk < 2; ++kk)
            af[mt][kk] = *(const bf16x8*)(Als + (w * 32 + mt * 16 + fm) * 64
                                          + (((kk * 4 + quad) ^ sw8) << 3));
    #pragma unroll
    for (int nt = 0; nt < 4; ++nt)
        #pragma unroll
        for (int kk = 0; kk < 2; ++kk)
            bf[nt][kk] = *(const bf16x8*)(Bls + (nt * 16 + fm) * 64
                                          + (((kk * 4 + quad) ^ sw8) << 3));

    f32x4 acc[2][4];
    #pragma unroll
    for (int mt = 0; mt < 2; ++mt)
        #pragma unroll
        for (int nt = 0; nt < 4; ++nt)
            acc[mt][nt] = f32x4{0.f, 0.f, 0.f, 0.f};

    #pragma unroll
    for (int kk = 0; kk < 2; ++kk)
        #pragma unroll
        for (int mt = 0; mt < 2; ++mt)
            #pragma unroll
            for (int nt = 0; nt < 4; ++nt)
                acc[mt][nt] = __builtin_amdgcn_mfma_f32_16x16x32_bf16(
                    af[mt][kk], bf[nt][kk], acc[mt][nt], 0, 0, 0);

    const int rbase = (lane >> 4) * 4;
    #pragma unroll
    for (int mt = 0; mt < 2; ++mt) {
        #pragma unroll
        for (int nt = 0; nt < 4; ++nt) {
            #pragma unroll
            for (int r = 0; r < 4; ++r) {
                const int row = r0 + w * 32 + mt * 16 + rbase + r;
                const int col = nt * 16 + fm;
                out[(size_t)row * 64 + col] = 0.125f * acc[mt][nt][r];
            }
        }
    }
}

extern "C" void kernel_launch(void* const* d_in, const int* in_sizes, int n_in,
                              void* d_out, int out_size, void* d_ws, size_t ws_size,
                              hipStream_t stream)
{
    const float* x  = (const float*)d_in[0];
    const float* Wq = (const float*)d_in[1];
    const float* bq = (const float*)d_in[2];
    const float* Wk = (const float*)d_in[3];
    const float* bk = (const float*)d_in[4];
    const float* Wv = (const float*)d_in[5];
    const float* bv = (const float*)d_in[6];
    float* wsf = (float*)d_ws;
    unsigned short* wsu = (unsigned short*)d_ws;
    float* out = (float*)d_out;

    dim3 gCvt(512, 7);
    cvt_bf16<<<gCvt, 256, 0, stream>>>(x, Wq, Wk, Wv, wsu + XB_U);

    dim3 gA(N_ROWS / 128, E_DIM / 128, 3);   // 32 x 8 x 3
    qkv_gemm_mfma<<<gA, 256, 0, stream>>>(wsu + XB_U, wsu + WB_U,
                                          bq, bk, bv, wsu + QB_U);

    dim3 gB(32, 8);
    kT_mfma<<<gB, 256, 0, stream>>>(wsu, wsf + P_F);

    reduce_T<<<512, 256, 0, stream>>>(wsf + P_F, wsu + TB_U);

    qT_mfma<<<512, 256, 0, stream>>>(wsu, wsu + TB_U, out);
}